// Round 1
// baseline (125.227 us; speedup 1.0000x reference)
//
#include <hip/hip_runtime.h>

#define EMB  128
#define HID4 2048   // 4*HID
#define WIN  128

// One block per batch row b.
// Phase 1: u[f] = sum_e ctr[b,e] * Wb[e,f]            (Wb L2-resident)
// Phase 2: online-softmax pass over the 128 window rows, each read ONCE:
//          half-wave hw (32 lanes x float4 = 128 floats) owns w = i*8+hw,
//          dot via shfl_xor reduce, running (m, Z, acc[128]) update.
// Phase 3: combine 8 half-wave partials -> context_eos[128]
// Phase 4: logits[b] = ci[b,:]·WL[:2048] + ceos·WL[2048:2176] + bL
__global__ __launch_bounds__(256) void eos_fused_kernel(
    const float* __restrict__ ci,        // [B, 2048]
    const float* __restrict__ window,    // [B, 128, 128]
    const unsigned char* __restrict__ mask_raw, // layout auto-detected
    const float* __restrict__ ctr,       // [B, 128]
    const float* __restrict__ Wb,        // [128, 128]
    const float* __restrict__ WL,        // [2176]
    const float* __restrict__ bL,        // [1]
    float* __restrict__ out)             // [B]
{
    const int b    = blockIdx.x;
    const int tid  = threadIdx.x;
    const int lane = tid & 63;
    const int wave = tid >> 6;

    __shared__ float ctr_s[EMB];
    __shared__ float pu_s[2][EMB];
    __shared__ float u_s[EMB];           // reused later for context_eos
    __shared__ float acc_s[8][EMB];
    __shared__ float mz_s[8][2];
    __shared__ float red_s[4];
    __shared__ unsigned long long det_s[4][2];
    __shared__ int mode_s;

    // ---------- mask dtype/layout detection (uniform, deterministic) ----------
    // int32 0/1 words: no bytes set above byte0.  float32 0.0/1.0 words: only
    // {0x00000000, 0x3F800000}.  packed bool: misaligned nonzero bytes w.p. ~1.
    {
        const unsigned int* mw = (const unsigned int*)mask_raw;
        int hi = 0, nf = 0;
        if (tid < 128) {
            unsigned int v = mw[tid];
            hi = (v & 0xFFFFFF00u) ? 1 : 0;
            nf = (v != 0u && v != 0x3F800000u) ? 1 : 0;
        }
        unsigned long long bh = __ballot(hi);
        unsigned long long bf = __ballot(nf);
        if (lane == 0) { det_s[wave][0] = bh; det_s[wave][1] = bf; }
    }
    if (tid < EMB) ctr_s[tid] = ctr[(size_t)b * EMB + tid];
    __syncthreads();
    if (tid == 0) {
        unsigned long long ah = det_s[0][0] | det_s[1][0] | det_s[2][0] | det_s[3][0];
        unsigned long long af = det_s[0][1] | det_s[1][1] | det_s[2][1] | det_s[3][1];
        mode_s = (af == 0ULL) ? 2 : (ah ? 0 : 1);   // 2=f32, 0=u8/bool, 1=i32
    }

    // ---------- u = ctr^T * Wb (e-dim split across the two block halves) ----
    {
        const int f  = tid & (EMB - 1);
        const int h  = tid >> 7;
        const int e0 = h * 64;
        float s = 0.f;
        #pragma unroll 8
        for (int e = 0; e < 64; ++e)
            s = fmaf(ctr_s[e0 + e], Wb[(e0 + e) * EMB + f], s);
        pu_s[h][f] = s;
    }
    __syncthreads();
    if (tid < EMB) u_s[tid] = pu_s[0][tid] + pu_s[1][tid];
    __syncthreads();

    const int mode = mode_s;
    const int hl   = lane & 31;              // lane within half-wave
    const int hw   = wave * 2 + (lane >> 5); // half-wave id 0..7
    float4 u4;
    u4.x = u_s[hl*4+0]; u4.y = u_s[hl*4+1]; u4.z = u_s[hl*4+2]; u4.w = u_s[hl*4+3];

    const float4*        win4 = (const float4*)(window + (size_t)b * WIN * EMB);
    const unsigned char* m8   = mask_raw + (size_t)b * WIN;
    const int*           m32  = (const int*)mask_raw + (size_t)b * WIN;
    const float*         mf   = (const float*)mask_raw + (size_t)b * WIN;

    float  m_run = -1e30f, Z = 0.f;
    float4 acc = make_float4(0.f, 0.f, 0.f, 0.f);

    #pragma unroll 4
    for (int i = 0; i < 16; ++i) {
        const int w = i * 8 + hw;
        float4 wv = win4[w * 32 + hl];       // wave reads 1 KB contiguous
        bool valid;
        if (mode == 0)      valid = (m8[w]  != 0);
        else if (mode == 1) valid = (m32[w] != 0);
        else                valid = (mf[w]  != 0.0f);
        float s = wv.x * u4.x;
        s = fmaf(wv.y, u4.y, s);
        s = fmaf(wv.z, u4.z, s);
        s = fmaf(wv.w, u4.w, s);
        s += __shfl_xor(s, 1);
        s += __shfl_xor(s, 2);
        s += __shfl_xor(s, 4);
        s += __shfl_xor(s, 8);
        s += __shfl_xor(s, 16);              // 32-lane dot -> all lanes of half
        const float m_new = valid ? fmaxf(m_run, s) : m_run;
        const float scale = __expf(m_run - m_new);   // ==1 while m_run sentinel
        const float p     = valid ? __expf(s - m_new) : 0.f;
        Z = fmaf(Z, scale, p);
        acc.x = fmaf(acc.x, scale, p * wv.x);
        acc.y = fmaf(acc.y, scale, p * wv.y);
        acc.z = fmaf(acc.z, scale, p * wv.z);
        acc.w = fmaf(acc.w, scale, p * wv.w);
        m_run = m_new;
    }

    acc_s[hw][hl*4+0] = acc.x;
    acc_s[hw][hl*4+1] = acc.y;
    acc_s[hw][hl*4+2] = acc.z;
    acc_s[hw][hl*4+3] = acc.w;
    if (hl == 0) { mz_s[hw][0] = m_run; mz_s[hw][1] = Z; }
    __syncthreads();

    // ---------- combine the 8 online-softmax partials ----------
    float ce = 0.f;
    if (tid < EMB) {
        float M = mz_s[0][0];
        #pragma unroll
        for (int p = 1; p < 8; ++p) M = fmaxf(M, mz_s[p][0]);
        float Zt = 0.f, a = 0.f;
        #pragma unroll
        for (int p = 0; p < 8; ++p) {
            const float sc = __expf(mz_s[p][0] - M);
            Zt = fmaf(mz_s[p][1], sc, Zt);
            a  = fmaf(acc_s[p][tid], sc, a);
        }
        ce = a / Zt;
    }
    __syncthreads();
    if (tid < EMB) u_s[tid] = ce;            // u_s now holds context_eos
    __syncthreads();

    // ---------- final linear: ci·WL[:2048] + ceos·WL[2048:] + b ----------
    const float4* ci4 = (const float4*)(ci + (size_t)b * HID4);
    const float4* wl4 = (const float4*)WL;
    float part;
    {
        float4 c0 = ci4[tid],       w0 = wl4[tid];
        float4 c1 = ci4[tid + 256], w1 = wl4[tid + 256];
        part = c0.x * w0.x;
        part = fmaf(c0.y, w0.y, part);
        part = fmaf(c0.z, w0.z, part);
        part = fmaf(c0.w, w0.w, part);
        part = fmaf(c1.x, w1.x, part);
        part = fmaf(c1.y, w1.y, part);
        part = fmaf(c1.z, w1.z, part);
        part = fmaf(c1.w, w1.w, part);
    }
    if (tid < EMB) part = fmaf(u_s[tid], WL[HID4 + tid], part);

    part += __shfl_xor(part, 1);
    part += __shfl_xor(part, 2);
    part += __shfl_xor(part, 4);
    part += __shfl_xor(part, 8);
    part += __shfl_xor(part, 16);
    part += __shfl_xor(part, 32);
    if (lane == 0) red_s[wave] = part;
    __syncthreads();
    if (tid == 0)
        out[b] = red_s[0] + red_s[1] + red_s[2] + red_s[3] + bL[0];
}

extern "C" void kernel_launch(void* const* d_in, const int* in_sizes, int n_in,
                              void* d_out, int out_size, void* d_ws, size_t ws_size,
                              hipStream_t stream) {
    const float*         ci     = (const float*)d_in[0];
    const float*         window = (const float*)d_in[1];
    const unsigned char* mask   = (const unsigned char*)d_in[2];
    const float*         ctr    = (const float*)d_in[3];
    const float*         Wb     = (const float*)d_in[4];
    const float*         WL     = (const float*)d_in[5];
    const float*         bL     = (const float*)d_in[6];
    float*               out    = (float*)d_out;

    const int B = in_sizes[0] / HID4;   // 8192
    hipLaunchKernelGGL(eos_fused_kernel, dim3(B), dim3(256), 0, stream,
                       ci, window, mask, ctr, Wb, WL, bL, out);
}